// Round 1
// baseline (4905.858 us; speedup 1.0000x reference)
//
#include <hip/hip_runtime.h>
#include <stdint.h>

// Sizes: x [16,1,512,512] f32 binary; weight [1024,512] f32; out [16,1,1024,529] f32.
// pot[b,o,t'] = sum_tau K(w[o,i],tau) * x[b,i,t'+15-tau] + 12.8, K = max(0,min(tau/16, 1.5w - tau/32))
// Strategy: K reconstructed via cumsum^2 of its 2nd difference (<=7 nonzero taps),
// scattered at spike positions. WTA's depression is provably uniform across neurons
// -> single per-batch refractory counter.

#define NB 16
#define NI 512
#define NT 512
#define NO 1024
#define TOUT 529
#define EEXT 544          // extended time axis: e = t' + 15, e in [0,544)
#define SCAP 96           // spike-list capacity per (b,i); mean 25.6, +7sigma ~ 60
#define THETA_F 25.6f
#define BIAS_T 12.8f

// ---------- P1: spike extraction (ballot compaction, 1 wave per (b,i) row) ----------
__global__ __launch_bounds__(256) void k_spikes(const float* __restrict__ x,
                                                unsigned short* __restrict__ slist,
                                                unsigned int* __restrict__ counts) {
    int wq = threadIdx.x >> 6, lane = threadIdx.x & 63;
    int row = blockIdx.x * 4 + wq;                 // row = b*512 + i, 8192 rows
    const float* xr = x + (size_t)row * NT;
    unsigned short* sl = slist + (size_t)row * SCAP;
    int base = 0;
    for (int k = 0; k < 8; ++k) {
        int t = k * 64 + lane;
        bool pred = xr[t] > 0.5f;
        unsigned long long mask = __ballot(pred);
        int pre = __popcll(mask & ((1ull << lane) - 1ull));
        if (pred) { int pos = base + pre; if (pos < SCAP) sl[pos] = (unsigned short)t; }
        base += __popcll(mask);
    }
    if (lane == 0) counts[row] = (unsigned int)min(base, SCAP);
}

// ---------- P2: per-(o,i) second-difference tap table ----------
// Linear regions give EXACTLY zero d in fp32 (tau/16, tau/32 exact; b15 - tau/32 exact
// while >= 0), so nonzeros only at onset/peak/cutoff/array-end: <= 7 taps.
__global__ __launch_bounds__(256) void k_taps(const float* __restrict__ weight,
                                              float* __restrict__ tapval,
                                              unsigned int* __restrict__ tappos) {
    int p = blockIdx.x * 256 + threadIdx.x;        // 1024*512 pairs
    int i = p >> 10, o = p & 1023;                 // i-major so o is coalesced on store
    float w = weight[o * NI + i];
    float b15 = 1.5f * w;
    float vals[8]; int poss[8];
#pragma unroll
    for (int j = 0; j < 8; ++j) { vals[j] = 0.f; poss[j] = 0; }
    int cnt = 0;
    float Km1 = 0.f, Km2 = 0.f;
    for (int tau = 0; tau <= 49; ++tau) {
        float K = 0.f;
        if (tau <= 47) {
            float f = (float)tau * 0.0625f;
            float g = b15 - (float)tau * 0.03125f;
            K = fmaxf(0.f, fminf(f, g));
        }
        float d = (K - Km1) - (Km1 - Km2);
        if (d != 0.f && cnt < 8) { vals[cnt] = d; poss[cnt] = tau; ++cnt; }
        Km2 = Km1; Km1 = K;
    }
#pragma unroll
    for (int j = 0; j < 8; ++j)
        tapval[(((size_t)i * 8 + j) << 10) + o] = vals[j];
    unsigned int tp0 = (unsigned)poss[0] | ((unsigned)poss[1] << 8) | ((unsigned)poss[2] << 16) | ((unsigned)poss[3] << 24);
    unsigned int tp1 = (unsigned)poss[4] | ((unsigned)poss[5] << 8) | ((unsigned)poss[6] << 16) | ((unsigned)poss[7] << 24);
    tappos[(((size_t)i * 2 + 0) << 10) + o] = tp0;
    tappos[(((size_t)i * 2 + 1) << 10) + o] = tp1;
}

// ---------- P3: scatter taps at spike positions + fused cumsum^2 + pot write ----------
// Block = (o-tile of 16, batch b). LDS acc [16][545] = 34.9 KB -> 4 blocks/CU.
// tid&15 = o_rel (coalesced tap loads), tid>>4 = 16-way spike split.
__global__ __launch_bounds__(256) void k_scatter(const unsigned short* __restrict__ slist,
                                                 const unsigned int* __restrict__ counts,
                                                 const float* __restrict__ tapval,
                                                 const unsigned int* __restrict__ tappos,
                                                 float* __restrict__ pot) {
    __shared__ float acc[16 * 545];                // stride 545 (odd) breaks bank aliasing
    const int o0 = blockIdx.x * 16;
    const int b  = blockIdx.y;
    const int tid = threadIdx.x;
    const int orl = tid & 15;
    const int sub = tid >> 4;                      // 0..15
    for (int idx = tid; idx < 16 * 545; idx += 256) acc[idx] = 0.f;
    __syncthreads();
    const int o = o0 + orl;
    for (int i = 0; i < NI; ++i) {
        int cnt = (int)counts[b * NI + i];
        if (cnt == 0) continue;
        float tv[8];
#pragma unroll
        for (int j = 0; j < 8; ++j) tv[j] = tapval[(((size_t)i * 8 + j) << 10) + o];
        unsigned int tp0 = tappos[(((size_t)i * 2 + 0) << 10) + o];
        unsigned int tp1 = tappos[(((size_t)i * 2 + 1) << 10) + o];
        const unsigned short* sl = slist + (size_t)(b * NI + i) * SCAP;
        for (int k = sub; k < cnt; k += 16) {
            int s = (int)sl[k];
#pragma unroll
            for (int j = 0; j < 8; ++j) {
                float v = tv[j];
                int pp = (j < 4) ? (int)((tp0 >> (8 * j)) & 255u) : (int)((tp1 >> (8 * (j - 4))) & 255u);
                int e = s + pp;                    // e = t' + 15; taps with e >= 544 only affect t' > 528
                if (v != 0.f && e < EEXT) atomicAdd(&acc[orl * 545 + e], v);
            }
        }
    }
    __syncthreads();
    if (tid < 16) {                                // exact-ish double cumsum^2
        double s1 = 0.0, s2 = 0.0;
        float* row = acc + tid * 545;
        for (int e = 0; e < EEXT; ++e) { s1 += (double)row[e]; s2 += s1; row[e] = (float)s2; }
    }
    __syncthreads();
    for (int idx = tid; idx < 16 * TOUT; idx += 256) {   // coalesced pot write (t fastest)
        int oo = idx / TOUT, t = idx - oo * TOUT;
        pot[((size_t)(b * NO + o0 + oo)) * TOUT + t] = acc[oo * 545 + t + 15] + BIAS_T;
    }
}

// ---------- P4: per-(b,t) argmax over 1024 neurons, first-index tie-break ----------
__global__ __launch_bounds__(256) void k_argmax(const float* __restrict__ pot,
                                                float* __restrict__ aval,
                                                unsigned short* __restrict__ aidx) {
    __shared__ float sv[4][64];
    __shared__ int   si[4][64];
    int b = blockIdx.y;
    int t0 = blockIdx.x * 64;
    int lane = threadIdx.x & 63, grp = threadIdx.x >> 6;
    int t = t0 + lane;
    bool valid = t < TOUT;
    float best = -1.f; int bidx = 0;
    if (valid) {
        for (int od = 0; od < 256; ++od) {         // ascending o + strict '>' => first max wins
            int o = grp * 256 + od;
            float v = pot[((size_t)(b * NO + o)) * TOUT + t];
            if (v > best) { best = v; bidx = o; }
        }
    }
    sv[grp][lane] = best; si[grp][lane] = bidx;
    __syncthreads();
    if (grp == 0 && valid) {
#pragma unroll
        for (int g = 1; g < 4; ++g) {
            float v = sv[g][lane];
            if (v > best) { best = v; bidx = si[g][lane]; }
        }
        aval[t * NB + b] = best;
        aidx[t * NB + b] = (unsigned short)bidx;
    }
}

// ---------- P5: serial refractory scan (depression is uniform across neurons) ----------
__global__ __launch_bounds__(256) void k_wta(const float* __restrict__ aval,
                                             const unsigned short* __restrict__ aidx,
                                             float* __restrict__ out) {
    __shared__ float lv[TOUT * NB];
    __shared__ unsigned short li[TOUT * NB];
    for (int idx = threadIdx.x; idx < TOUT * NB; idx += 256) { lv[idx] = aval[idx]; li[idx] = aidx[idx]; }
    __syncthreads();
    int b = threadIdx.x;
    if (b < NB) {
        int r = 0;                                 // dep counter: active iff r==0
        for (int t = 0; t < TOUT; ++t) {
            float v = lv[t * NB + b];
            if (r == 0 && v > THETA_F) {
                int n = (int)li[t * NB + b];
                out[((size_t)(b * NO + n)) * TOUT + t] = 1.0f;
                r = 48;                            // dep += 48, then -1 & clip below
            }
            r = max(r - 1, 0);
        }
    }
}

extern "C" void kernel_launch(void* const* d_in, const int* in_sizes, int n_in,
                              void* d_out, int out_size, void* d_ws, size_t ws_size,
                              hipStream_t stream) {
    const float* x      = (const float*)d_in[0];   // [16,1,512,512]
    const float* weight = (const float*)d_in[1];   // [1024,512]
    float* out = (float*)d_out;                    // [16,1,1024,529]
    char* ws = (char*)d_ws;
    // ws layout (~22.6 MB total)
    unsigned short* slist = (unsigned short*)(ws);                 // 16*512*96*2   = 1,572,864
    unsigned int*   counts = (unsigned int*)(ws + 1572864);        // 16*512*4      = 32,768
    float*          tapval = (float*)(ws + 1605632);               // 512*8*1024*4  = 16,777,216
    unsigned int*   tappos = (unsigned int*)(ws + 18382848);       // 512*2*1024*4  = 4,194,304
    float*          aval   = (float*)(ws + 22577152);              // 529*16*4      = 33,856
    unsigned short* aidx   = (unsigned short*)(ws + 22611008);     // 529*16*2      = 16,928

    k_spikes<<<2048, 256, 0, stream>>>(x, slist, counts);
    k_taps<<<2048, 256, 0, stream>>>(weight, tapval, tappos);
    k_scatter<<<dim3(64, 16), 256, 0, stream>>>(slist, counts, tapval, tappos, out); // pot -> d_out
    k_argmax<<<dim3(9, 16), 256, 0, stream>>>(out, aval, aidx);
    hipMemsetAsync(d_out, 0, (size_t)out_size * sizeof(float), stream);              // clear pot
    k_wta<<<1, 256, 0, stream>>>(aval, aidx, out);                                   // write spikes
}